// Round 1
// baseline (146.987 us; speedup 1.0000x reference)
//
#include <hip/hip_runtime.h>

constexpr int F = 2048;          // NUM_FEATURES
constexpr int NROWS = 8192;      // rows
constexpr float EPS = 1e-6f;
constexpr int ROWS_PER_BLOCK = 32;
constexpr int STRIDE4 = F / 4;   // 512 float4 per row

// Pass 1: per-column partial sum / sumsq, atomically accumulated into acc[0:F) (sum)
// and acc[F:2F) (sumsq). Grid: (2, NROWS/ROWS_PER_BLOCK), block 256.
// Each thread owns 4 consecutive columns (one float4) and ROWS_PER_BLOCK rows.
__global__ void reduce_kernel(const float* __restrict__ x, float* __restrict__ acc) {
    const int c4 = blockIdx.x * blockDim.x + threadIdx.x;   // 0..511 float4 column index
    const int row0 = blockIdx.y * ROWS_PER_BLOCK;
    const float4* __restrict__ xv = reinterpret_cast<const float4*>(x);

    float4 s  = make_float4(0.f, 0.f, 0.f, 0.f);
    float4 ss = make_float4(0.f, 0.f, 0.f, 0.f);

    size_t base = (size_t)row0 * STRIDE4 + (size_t)c4;
#pragma unroll
    for (int r = 0; r < ROWS_PER_BLOCK; ++r) {
        float4 v = xv[base + (size_t)r * STRIDE4];
        s.x += v.x;  s.y += v.y;  s.z += v.z;  s.w += v.w;
        ss.x += v.x * v.x;  ss.y += v.y * v.y;  ss.z += v.z * v.z;  ss.w += v.w * v.w;
    }

    float* sum   = acc;
    float* sumsq = acc + F;
    const int c = c4 * 4;
    atomicAdd(&sum[c + 0], s.x);
    atomicAdd(&sum[c + 1], s.y);
    atomicAdd(&sum[c + 2], s.z);
    atomicAdd(&sum[c + 3], s.w);
    atomicAdd(&sumsq[c + 0], ss.x);
    atomicAdd(&sumsq[c + 1], ss.y);
    atomicAdd(&sumsq[c + 2], ss.z);
    atomicAdd(&sumsq[c + 3], ss.w);
}

// Pass 2: mean / rstd per column. stats[0:F) = mean, stats[F:2F) = rsqrt(var+eps).
__global__ void finalize_kernel(const float* __restrict__ acc, float* __restrict__ stats) {
    const int c = blockIdx.x * blockDim.x + threadIdx.x;
    if (c < F) {
        const float s1 = acc[c];
        const float s2 = acc[c + F];
        const float invN = 1.0f / (float)NROWS;
        const float mean = s1 * invN;
        float var = (s2 - s1 * mean) * (1.0f / (float)(NROWS - 1));
        var = fmaxf(var, 0.0f);
        stats[c]     = mean;
        stats[c + F] = rsqrtf(var + EPS);
    }
}

// Pass 3: out = (x - mean[col]) * rstd[col], float4 streaming.
__global__ void normalize_kernel(const float* __restrict__ x,
                                 const float* __restrict__ stats,
                                 float* __restrict__ out) {
    const size_t i = (size_t)blockIdx.x * blockDim.x + threadIdx.x;  // float4 index
    const float4* __restrict__ xv    = reinterpret_cast<const float4*>(x);
    float4* __restrict__ ov          = reinterpret_cast<float4*>(out);
    const float4* __restrict__ meanv = reinterpret_cast<const float4*>(stats);
    const float4* __restrict__ rstdv = reinterpret_cast<const float4*>(stats + F);

    const int c4 = (int)(i & (STRIDE4 - 1));  // column float4 index (512 is pow2)
    float4 v = xv[i];
    float4 m = meanv[c4];
    float4 r = rstdv[c4];
    float4 o;
    o.x = (v.x - m.x) * r.x;
    o.y = (v.y - m.y) * r.y;
    o.z = (v.z - m.z) * r.z;
    o.w = (v.w - m.w) * r.w;
    ov[i] = o;
}

extern "C" void kernel_launch(void* const* d_in, const int* in_sizes, int n_in,
                              void* d_out, int out_size, void* d_ws, size_t ws_size,
                              hipStream_t stream) {
    const float* x = (const float*)d_in[0];
    // d_in[1] (running_mean) and d_in[2] (running_var) are mathematically wiped
    // by the Welford recurrence at n=1 / n=2 respectively — not needed.
    float* out   = (float*)d_out;
    float* acc   = (float*)d_ws;       // [0:F) sum, [F:2F) sumsq
    float* stats = acc + 2 * F;        // [0:F) mean, [F:2F) rstd

    // ws is poisoned 0xAA before every call — zero the accumulators.
    hipMemsetAsync(d_ws, 0, 2 * F * sizeof(float), stream);

    reduce_kernel<<<dim3(2, NROWS / ROWS_PER_BLOCK), 256, 0, stream>>>(x, acc);
    finalize_kernel<<<F / 256, 256, 0, stream>>>(acc, stats);

    const int total4 = NROWS * STRIDE4;           // 4,194,304 float4 elements
    normalize_kernel<<<total4 / 256, 256, 0, stream>>>(x, stats, out);
}

// Round 2
// 132.789 us; speedup vs baseline: 1.1069x; 1.1069x over previous
//
#include <hip/hip_runtime.h>

constexpr int F = 2048;          // NUM_FEATURES
constexpr int NROWS = 8192;      // rows
constexpr float EPS = 1e-6f;
constexpr int STRIDE4 = F / 4;   // 512 float4 per row

// ---------------------------------------------------------------------------
// Pass 1: per-column partial sum / sumsq.
// Grid (8, 128), block 256. Block covers 64 float4-columns x 64 rows.
// Threads: lc = tid&63 (column), sg = tid>>6 (row subgroup, 16 rows each).
// LDS reduces the 4 subgroups so only 64 threads/block do atomics
// (1024 blocks * 64 thr * 8 atomics = 524k atomic float adds, was 1M).
// ---------------------------------------------------------------------------
__global__ __launch_bounds__(256) void reduce_kernel(const float* __restrict__ x,
                                                     float* __restrict__ acc) {
    __shared__ float4 lS[3 * 64];
    __shared__ float4 lQ[3 * 64];

    const int lc = threadIdx.x & 63;
    const int sg = threadIdx.x >> 6;
    const int c4 = blockIdx.x * 64 + lc;
    const int row0 = blockIdx.y * 64 + sg * 16;
    const float4* __restrict__ xv = reinterpret_cast<const float4*>(x);

    float4 s = make_float4(0.f, 0.f, 0.f, 0.f);
    float4 q = make_float4(0.f, 0.f, 0.f, 0.f);

    size_t base = (size_t)row0 * STRIDE4 + (size_t)c4;
#pragma unroll
    for (int r = 0; r < 16; ++r) {
        float4 v = xv[base + (size_t)r * STRIDE4];
        s.x += v.x;  s.y += v.y;  s.z += v.z;  s.w += v.w;
        q.x += v.x * v.x;  q.y += v.y * v.y;  q.z += v.z * v.z;  q.w += v.w * v.w;
    }

    if (sg != 0) {
        lS[(sg - 1) * 64 + lc] = s;
        lQ[(sg - 1) * 64 + lc] = q;
    }
    __syncthreads();

    if (sg == 0) {
#pragma unroll
        for (int k = 0; k < 3; ++k) {
            float4 t = lS[k * 64 + lc];
            float4 u = lQ[k * 64 + lc];
            s.x += t.x;  s.y += t.y;  s.z += t.z;  s.w += t.w;
            q.x += u.x;  q.y += u.y;  q.z += u.z;  q.w += u.w;
        }
        float* __restrict__ sum   = acc;
        float* __restrict__ sumsq = acc + F;
        const int c = c4 * 4;
        atomicAdd(&sum[c + 0], s.x);
        atomicAdd(&sum[c + 1], s.y);
        atomicAdd(&sum[c + 2], s.z);
        atomicAdd(&sum[c + 3], s.w);
        atomicAdd(&sumsq[c + 0], q.x);
        atomicAdd(&sumsq[c + 1], q.y);
        atomicAdd(&sumsq[c + 2], q.z);
        atomicAdd(&sumsq[c + 3], q.w);
    }
}

// ---------------------------------------------------------------------------
// Pass 2: stats[c] = rstd, stats[c+F] = -mean*rstd  (so normalize is one FMA).
// ---------------------------------------------------------------------------
__global__ void finalize_kernel(const float* __restrict__ acc, float* __restrict__ stats) {
    const int c = blockIdx.x * blockDim.x + threadIdx.x;
    if (c < F) {
        const float s1 = acc[c];
        const float s2 = acc[c + F];
        const float invN = 1.0f / (float)NROWS;
        const float mean = s1 * invN;
        float var = (s2 - s1 * mean) * (1.0f / (float)(NROWS - 1));
        var = fmaxf(var, 0.0f);
        const float r = rsqrtf(var + EPS);
        stats[c]     = r;
        stats[c + F] = -mean * r;
    }
}

// ---------------------------------------------------------------------------
// Pass 3: out = x * r + b, float4 streaming, 2 float4 per thread for ILP.
// ---------------------------------------------------------------------------
constexpr int TOTAL4 = NROWS * STRIDE4;          // 4,194,304 float4
constexpr int HALF4  = TOTAL4 / 2;

__global__ __launch_bounds__(256) void normalize_kernel(const float* __restrict__ x,
                                                        const float* __restrict__ stats,
                                                        float* __restrict__ out) {
    const size_t i = (size_t)blockIdx.x * blockDim.x + threadIdx.x;  // float4 index
    const float4* __restrict__ xv = reinterpret_cast<const float4*>(x);
    float4* __restrict__ ov       = reinterpret_cast<float4*>(out);
    const float4* __restrict__ rv = reinterpret_cast<const float4*>(stats);
    const float4* __restrict__ bv = reinterpret_cast<const float4*>(stats + F);

#pragma unroll
    for (int h = 0; h < 2; ++h) {
        const size_t idx = i + (size_t)h * HALF4;
        const int c4 = (int)(idx & (STRIDE4 - 1));
        float4 v = xv[idx];
        float4 r = rv[c4];
        float4 b = bv[c4];
        float4 o;
        o.x = fmaf(v.x, r.x, b.x);
        o.y = fmaf(v.y, r.y, b.y);
        o.z = fmaf(v.z, r.z, b.z);
        o.w = fmaf(v.w, r.w, b.w);
        ov[idx] = o;
    }
}

extern "C" void kernel_launch(void* const* d_in, const int* in_sizes, int n_in,
                              void* d_out, int out_size, void* d_ws, size_t ws_size,
                              hipStream_t stream) {
    const float* x = (const float*)d_in[0];
    // running_mean / running_var are wiped by the Welford recurrence (n=1 / n=2).
    float* out   = (float*)d_out;
    float* acc   = (float*)d_ws;       // [0:F) sum, [F:2F) sumsq
    float* stats = acc + 2 * F;        // [0:F) rstd, [F:2F) -mean*rstd

    hipMemsetAsync(d_ws, 0, 2 * F * sizeof(float), stream);

    reduce_kernel<<<dim3(8, NROWS / 64), 256, 0, stream>>>(x, acc);
    finalize_kernel<<<F / 256, 256, 0, stream>>>(acc, stats);
    normalize_kernel<<<HALF4 / 256, 256, 0, stream>>>(x, stats, out);
}